// Round 1
// baseline (5196.744 us; speedup 1.0000x reference)
//
#include <hip/hip_runtime.h>
#include <hip/hip_bf16.h>

typedef __bf16 bf16;
typedef __bf16 bf16x8 __attribute__((ext_vector_type(8)));
typedef float f32x4 __attribute__((ext_vector_type(4)));

#define B_ 16
#define T_ 241
#define H_ 1024
#define NC_ 100
#define TE_ 512
#define BT_ 3856   // B_*T_
#define OUT0_ 385600
#define OUT1_ 7897088
#define SEGCAP_ 3872

// ---------------- utility kernels ----------------

__global__ void zero_fill(unsigned* __restrict__ p, long n) {
    for (long i = (long)blockIdx.x * blockDim.x + threadIdx.x; i < n;
         i += (long)gridDim.x * blockDim.x) p[i] = 0u;
}

__global__ void bias_sum(const float* a0, const float* b0, const float* a1,
                         const float* b1, float* o0, float* o1) {
    int i = blockIdx.x * blockDim.x + threadIdx.x;
    if (i < 4096) { o0[i] = a0[i] + b0[i]; o1[i] = a1[i] + b1[i]; }
}

__global__ void f2bf(const float* __restrict__ in, bf16* __restrict__ out, long n) {
    for (long i = (long)blockIdx.x * blockDim.x + threadIdx.x; i < n;
         i += (long)gridDim.x * blockDim.x) out[i] = (bf16)in[i];
}

__global__ void embed_gather(const int* __restrict__ tg, const float* __restrict__ embw,
                             bf16* __restrict__ out, long n) {
    for (long i = (long)blockIdx.x * blockDim.x + threadIdx.x; i < n;
         i += (long)gridDim.x * blockDim.x) {
        int bt = (int)(i >> 10), d = (int)(i & 1023);
        out[i] = (bf16)embw[(long)tg[bt] * H_ + d];
    }
}

__global__ void pack_w1(const float* __restrict__ wih, const float* __restrict__ whh,
                        bf16* __restrict__ out) {
    long n = (long)4096 * 2048;
    for (long i = (long)blockIdx.x * blockDim.x + threadIdx.x; i < n;
         i += (long)gridDim.x * blockDim.x) {
        int r = (int)(i >> 11), k = (int)(i & 2047);
        float v = (k < 1024) ? wih[(long)r * 1024 + k] : whh[(long)r * 1024 + (k - 1024)];
        out[i] = (bf16)v;
    }
}

// out[n][k] = in[k][n], n < Cp (zero pad beyond C)
__global__ void transpose_bf16(const float* __restrict__ in, bf16* __restrict__ out,
                               int R, int C, int Cp) {
    __shared__ float tile[32][33];
    int k0 = blockIdx.x * 32, n0 = blockIdx.y * 32;
    int tx = threadIdx.x & 31, ty = threadIdx.x >> 5;  // 32x8
    for (int yy = ty; yy < 32; yy += 8) {
        int k = k0 + yy, n = n0 + tx;
        tile[yy][tx] = (k < R && n < C) ? in[(long)k * C + n] : 0.f;
    }
    __syncthreads();
    for (int yy = ty; yy < 32; yy += 8) {
        int n = n0 + yy, k = k0 + tx;
        if (n < Cp && k < R) out[(long)n * R + k] = (bf16)tile[tx][yy];
    }
}

// ---------------- generic A(row-major bf16) x Bt(row-major bf16) GEMM ----------------

struct GemmArgs {
    const bf16* A; long sAb; long sAh; int lda;
    const bf16* Bt; long sBb; long sBh; int ldb;
    float* C; long sCb; long sCh; int ldc;
    bf16* Cb; long sCbb; long sCbh; int ldcb;
    const float* biasCol; const float* biasRow;
    int M; int N; int K; int nh; int act;
};

__global__ void __launch_bounds__(256) gemm_bt(GemmArgs g) {
    int z = blockIdx.z;
    int zb = z / g.nh, zh = z - zb * g.nh;
    const bf16* A  = g.A  + (long)zb * g.sAb + (long)zh * g.sAh;
    const bf16* Bt = g.Bt + (long)zb * g.sBb + (long)zh * g.sBh;
    int wave = threadIdx.x >> 6, lane = threadIdx.x & 63;
    int l15 = lane & 15, kb = (lane >> 4) * 8;
    int mt0 = blockIdx.y * 4 + (wave >> 1) * 2;
    int ct0 = blockIdx.x * 4 + (wave & 1) * 2;
    const bf16* pa0 = A + (long)(mt0 * 16 + l15) * g.lda + kb;
    const bf16* pa1 = pa0 + (long)16 * g.lda;
    const bf16* pb0 = Bt + (long)(ct0 * 16 + l15) * g.ldb + kb;
    const bf16* pb1 = pb0 + (long)16 * g.ldb;
    f32x4 acc00 = {0.f,0.f,0.f,0.f}, acc01 = {0.f,0.f,0.f,0.f};
    f32x4 acc10 = {0.f,0.f,0.f,0.f}, acc11 = {0.f,0.f,0.f,0.f};
    for (int k = 0; k < g.K; k += 32) {
        bf16x8 a0 = *(const bf16x8*)(pa0 + k);
        bf16x8 a1 = *(const bf16x8*)(pa1 + k);
        bf16x8 b0 = *(const bf16x8*)(pb0 + k);
        bf16x8 b1 = *(const bf16x8*)(pb1 + k);
        acc00 = __builtin_amdgcn_mfma_f32_16x16x32_bf16(a0, b0, acc00, 0, 0, 0);
        acc01 = __builtin_amdgcn_mfma_f32_16x16x32_bf16(a0, b1, acc01, 0, 0, 0);
        acc10 = __builtin_amdgcn_mfma_f32_16x16x32_bf16(a1, b0, acc10, 0, 0, 0);
        acc11 = __builtin_amdgcn_mfma_f32_16x16x32_bf16(a1, b1, acc11, 0, 0, 0);
    }
    float* C  = g.C  ? g.C  + (long)zb * g.sCb  + (long)zh * g.sCh  : (float*)0;
    bf16*  Cb = g.Cb ? g.Cb + (long)zb * g.sCbb + (long)zh * g.sCbh : (bf16*)0;
    int rbase = (lane >> 4) * 4;
#pragma unroll
    for (int i = 0; i < 2; i++) {
#pragma unroll
        for (int j = 0; j < 2; j++) {
            f32x4 av = i ? (j ? acc11 : acc10) : (j ? acc01 : acc00);
            int colg = (ct0 + j) * 16 + l15;
            if (colg >= g.N) continue;
            float bc = g.biasCol ? g.biasCol[colg] : 0.f;
#pragma unroll
            for (int r = 0; r < 4; r++) {
                int rowg = (mt0 + i) * 16 + rbase + r;
                if (rowg >= g.M) continue;
                float val = av[r] + bc;
                if (g.biasRow) val += g.biasRow[rowg];
                if (g.act == 1) val = tanhf(val);
                if (C)  C[(long)rowg * g.ldc + colg] = val;
                if (Cb) Cb[(long)rowg * g.ldcb + colg] = (bf16)val;
            }
        }
    }
}

// ---------------- LSTM wavefront step (layer0 step s, layer1 step s-1) ----------------
// blocks 0..63: layer0 units [16*blk,16*blk+16); blocks 64..127: layer1.

__global__ void __launch_bounds__(256) lstm_step(
    const bf16* __restrict__ Whh0,   // [4096][1024]
    const bf16* __restrict__ W1pk,   // [4096][2048]  = [Wih1 | Whh1]
    const float* __restrict__ xg0,   // [16][241][4096] (biases folded)
    const float* __restrict__ bias1, // [4096]
    bf16* __restrict__ h0buf,        // [2][16][1024]
    bf16* __restrict__ A1buf,        // [2][16][2048]
    float* __restrict__ c0, float* __restrict__ c1,
    bf16* __restrict__ featsA,       // [3920][2048] (h1 into cols 0..1024)
    int s) {
    int blk = blockIdx.x;
    bool isL1 = blk >= 64;
    if (!isL1 && s >= 241) return;
    if (isL1 && s < 1) return;
    int wave = threadIdx.x >> 6, lane = threadIdx.x & 63;
    int l15 = lane & 15, kb = (lane >> 4) * 8;
    int ub = (isL1 ? blk - 64 : blk) * 16;
    int ng = wave * 1024 + ub + l15;  // Bt (gate) row
    f32x4 acc;
    { float iv = isL1 ? bias1[ng] : 0.f; acc[0]=iv; acc[1]=iv; acc[2]=iv; acc[3]=iv; }
    if (!isL1) {
        const bf16* pa = h0buf + ((s & 1) << 14) + l15 * 1024 + kb;
        const bf16* pb = Whh0 + (long)ng * 1024 + kb;
        for (int k = 0; k < 1024; k += 32) {
            bf16x8 a = *(const bf16x8*)(pa + k);
            bf16x8 b = *(const bf16x8*)(pb + k);
            acc = __builtin_amdgcn_mfma_f32_16x16x32_bf16(a, b, acc, 0, 0, 0);
        }
    } else {
        const bf16* pa = A1buf + ((s & 1) << 15) + l15 * 2048 + kb;
        const bf16* pb = W1pk + (long)ng * 2048 + kb;
        for (int k = 0; k < 2048; k += 32) {
            bf16x8 a = *(const bf16x8*)(pa + k);
            bf16x8 b = *(const bf16x8*)(pb + k);
            acc = __builtin_amdgcn_mfma_f32_16x16x32_bf16(a, b, acc, 0, 0, 0);
        }
    }
    __shared__ float gt[4][16][17];
#pragma unroll
    for (int r = 0; r < 4; r++) gt[wave][(lane >> 4) * 4 + r][l15] = acc[r];
    __syncthreads();
    int b = threadIdx.x >> 4, u = threadIdx.x & 15;
    float gi = gt[0][b][u], gf = gt[1][b][u], gg = gt[2][b][u], go = gt[3][b][u];
    int ug = ub + u;
    if (!isL1) {
        const float* xp = xg0 + ((long)b * 241 + s) * 4096 + ug;
        gi += xp[0]; gf += xp[1024]; gg += xp[2048]; go += xp[3072];
    }
    float* cs = isL1 ? c1 : c0;
    float c = cs[b * 1024 + ug];
    float si = 1.f / (1.f + expf(-gi));
    float sf = 1.f / (1.f + expf(-gf));
    float so = 1.f / (1.f + expf(-go));
    c = sf * c + si * tanhf(gg);
    float hv = so * tanhf(c);
    cs[b * 1024 + ug] = c;
    int pn = (s + 1) & 1;
    if (!isL1) {
        h0buf[(pn << 14) + b * 1024 + ug] = (bf16)hv;
        A1buf[(pn << 15) + b * 2048 + ug] = (bf16)hv;
    } else {
        A1buf[(pn << 15) + b * 2048 + 1024 + ug] = (bf16)hv;
        featsA[((long)b * 241 + (s - 1)) * 2048 + ug] = (bf16)hv;
    }
}

// ---------------- softmaxes ----------------

__global__ void __launch_bounds__(256) attn_softmax(float* __restrict__ attn,
                                                    bf16* __restrict__ attnb, int nrows) {
    int row = blockIdx.x * 4 + (threadIdx.x >> 6);
    int lane = threadIdx.x & 63;
    if (row >= nrows) return;
    float* p = attn + (long)row * 512;
    float v[8];
    float m = -1e30f;
#pragma unroll
    for (int j = 0; j < 8; j++) { v[j] = p[lane + 64 * j] * 0.0625f; m = fmaxf(m, v[j]); }
    for (int o = 32; o; o >>= 1) m = fmaxf(m, __shfl_xor(m, o));
    float ssum = 0.f;
#pragma unroll
    for (int j = 0; j < 8; j++) { v[j] = expf(v[j] - m); ssum += v[j]; }
    for (int o = 32; o; o >>= 1) ssum += __shfl_xor(ssum, o);
    float inv = 1.f / ssum;
#pragma unroll
    for (int j = 0; j < 8; j++) {
        float a = v[j] * inv;
        p[lane + 64 * j] = a;
        attnb[(long)row * 512 + lane + 64 * j] = (bf16)a;
    }
}

__global__ void __launch_bounds__(256) logsoftmax_k(float* __restrict__ out, int nrows) {
    int row = blockIdx.x * 4 + (threadIdx.x >> 6);
    int lane = threadIdx.x & 63;
    if (row >= nrows) return;
    float* p = out + (long)row * 100;
    float v0 = lane < 100 ? p[lane] : -1e30f;
    float v1 = lane < 36 ? p[64 + lane] : -1e30f;
    float m = fmaxf(v0, v1);
    for (int o = 32; o; o >>= 1) m = fmaxf(m, __shfl_xor(m, o));
    float s = (lane < 100 ? expf(v0 - m) : 0.f) + (lane < 36 ? expf(v1 - m) : 0.f);
    for (int o = 32; o; o >>= 1) s += __shfl_xor(s, o);
    float lg = m + logf(s);
    if (lane < 100) p[lane] = v0 - lg;
    if (lane < 36) p[64 + lane] = v1 - lg;
}

// ---------------- words ----------------

__global__ void seg_scan(const int* __restrict__ tg, int* __restrict__ meta) {
    __shared__ int st[16][242], ln[16][242];
    __shared__ int cnt[16], rmax[16], off[17];
    int b = threadIdx.x;
    if (b < 16) {
        const int* tok = tg + b * 241 + 1;
        int start = 0, n = 0, mx = 0; bool broke = false;
        for (int t = 0; t < 240; t++) {
            int v = tok[t];
            if (v == 1 || v == 2) {
                st[b][n] = start; ln[b][n] = t - start;
                if (t - start > mx) mx = t - start;
                n++; start = t + 1;
                if (v == 2) { broke = true; break; }
            }
        }
        if (!broke && start < 240) {
            st[b][n] = start; ln[b][n] = 240 - start;
            if (240 - start > mx) mx = 240 - start;
            n++;
        }
        cnt[b] = n; rmax[b] = mx;
    }
    __syncthreads();
    if (threadIdx.x == 0) {
        int tot = 0, mx = 0;
        for (int i = 0; i < 16; i++) { off[i] = tot; tot += cnt[i]; if (rmax[i] > mx) mx = rmax[i]; }
        off[16] = tot; meta[0] = tot; meta[1] = mx;
    }
    __syncthreads();
    if (b < 16) {
        int* segb = meta + 2; int* segs = segb + SEGCAP_; int* segl = segs + SEGCAP_;
        int o = off[b];
        for (int i = 0; i < cnt[b]; i++) { segb[o + i] = b; segs[o + i] = st[b][i]; segl[o + i] = ln[b][i]; }
    }
}

__global__ void words_fill(const int* __restrict__ meta, const int* __restrict__ tg,
                           const float* __restrict__ embw, const float* __restrict__ ctxf,
                           float* __restrict__ out2, long nelem) {
    int N = meta[0], mx = meta[1];
    const int* segb = meta + 2;
    const int* segs = segb + SEGCAP_;
    const int* segl = segs + SEGCAP_;
    unsigned wl = (unsigned)mx * 2048u;
    if (wl == 0) wl = 1u;
    for (long ee = (long)blockIdx.x * blockDim.x + threadIdx.x; ee < nelem;
         ee += (long)gridDim.x * blockDim.x) {
        unsigned e = (unsigned)ee;
        unsigned n = e / wl, rem = e - n * wl;
        unsigned l = rem >> 11, d = rem & 2047u;
        float val = 0.f;
        if ((int)n < N && (int)l < segl[n]) {
            int b = segb[n]; int tp = segs[n] + (int)l;  // index in sliced [0,240)
            if (d < 1024u) val = embw[(long)tg[b * 241 + tp + 1] * H_ + d];
            else val = ctxf[((long)b * 241 + tp) * H_ + (d - 1024u)];
        }
        out2[ee] = val;
    }
}

// ---------------- host ----------------

extern "C" void kernel_launch(void* const* d_in, const int* in_sizes, int n_in,
                              void* d_out, int out_size, void* d_ws, size_t ws_size,
                              hipStream_t stream) {
    const int*   targets = (const int*)d_in[0];
    const float* enc  = (const float*)d_in[1];
    const float* embw = (const float*)d_in[2];
    const float* wih0 = (const float*)d_in[3];
    const float* whh0 = (const float*)d_in[4];
    const float* bih0 = (const float*)d_in[5];
    const float* bhh0 = (const float*)d_in[6];
    const float* wih1 = (const float*)d_in[7];
    const float* whh1 = (const float*)d_in[8];
    const float* bih1 = (const float*)d_in[9];
    const float* bhh1 = (const float*)d_in[10];
    const float* wq = (const float*)d_in[11];
    const float* bq = (const float*)d_in[12];
    const float* wk = (const float*)d_in[13];
    const float* bk = (const float*)d_in[14];
    const float* wv = (const float*)d_in[15];
    const float* bv = (const float*)d_in[16];
    const float* w1 = (const float*)d_in[17];
    const float* b1 = (const float*)d_in[18];
    const float* w2 = (const float*)d_in[19];
    const float* b2 = (const float*)d_in[20];

    char* ws = (char*)d_ws;
    size_t off = 0;
    auto alloc = [&](size_t bytes) {
        char* p = ws + off; off += (bytes + 255) & ~(size_t)255; return p;
    };
    // state (zeroed each call; must stay contiguous)
    bf16* h0buf = (bf16*)alloc(65536);
    bf16* A1buf = (bf16*)alloc(131072);
    float* c0 = (float*)alloc(65536);
    float* c1 = (float*)alloc(65536);
    float* bias0 = (float*)alloc(16384);
    float* bias1f = (float*)alloc(16384);
    int* meta = (int*)alloc((2 + 3 * SEGCAP_) * 4);
    bf16* kbf = (bf16*)alloc((size_t)8192 * 1024 * 2);
    bf16* vT  = (bf16*)alloc((size_t)16 * 1024 * 512 * 2);
    bf16* wqT = (bf16*)alloc((size_t)1024 * 1024 * 2);
    bf16* w1T = (bf16*)alloc((size_t)1024 * 2048 * 2);
    bf16* w2T = (bf16*)alloc((size_t)128 * 1024 * 2);
    bf16* featsA = (bf16*)alloc((size_t)3920 * 2048 * 2);
    char* regB = alloc(63176704);              // xg0; reused after recurrence
    float* xg0  = (float*)regB;
    bf16* qbf   = (bf16*)regB;                           // 3920*1024*2 = 8028160
    bf16* attnb = (bf16*)(regB + 8028160);               // 15488*512*2 = 15859712
    float* ctxf = (float*)(regB + 8028160 + 15859712);   // 3856*1024*4 = 15794176
    bf16* xbf   = (bf16*)(regB + 39682048);              // 3920*1024*2
    bf16* embb  = (bf16*)alloc((size_t)3920 * 1024 * 2);
    bf16* encb  = (bf16*)alloc((size_t)8192 * 1024 * 2);
    bf16* wih0b = (bf16*)alloc((size_t)4096 * 1024 * 2);
    bf16* whh0b = (bf16*)alloc((size_t)4096 * 1024 * 2);
    bf16* w1pk  = (bf16*)alloc((size_t)4096 * 2048 * 2);
    bf16* wkT = (bf16*)alloc((size_t)1024 * 1024 * 2);
    bf16* wvT = (bf16*)alloc((size_t)1024 * 1024 * 2);
    (void)ws_size; (void)in_sizes; (void)n_in;

    auto gemm = [&](const bf16* A, long sAb, long sAh, int lda,
                    const bf16* Bt, long sBb, long sBh, int ldb,
                    float* C, long sCb, long sCh, int ldc,
                    bf16* Cb, long sCbb, long sCbh, int ldcb,
                    const float* bc, const float* br,
                    int M, int N, int K, int nh, int act, int Z) {
        GemmArgs ga{A, sAb, sAh, lda, Bt, sBb, sBh, ldb, C, sCb, sCh, ldc,
                    Cb, sCbb, sCbh, ldcb, bc, br, M, N, K, nh, act};
        dim3 grid((N + 63) / 64, (M + 63) / 64, Z);
        gemm_bt<<<grid, 256, 0, stream>>>(ga);
    };

    // prep
    zero_fill<<<64, 256, 0, stream>>>((unsigned*)h0buf, 81920);
    bias_sum<<<16, 256, 0, stream>>>(bih0, bhh0, bih1, bhh1, bias0, bias1f);
    seg_scan<<<1, 64, 0, stream>>>(targets, meta);
    embed_gather<<<2048, 256, 0, stream>>>(targets, embw, embb, (long)BT_ * 1024);
    f2bf<<<2048, 256, 0, stream>>>(enc, encb, (long)8192 * 1024);
    f2bf<<<2048, 256, 0, stream>>>(wih0, wih0b, (long)4096 * 1024);
    f2bf<<<2048, 256, 0, stream>>>(whh0, whh0b, (long)4096 * 1024);
    pack_w1<<<2048, 256, 0, stream>>>(wih1, whh1, w1pk);
    transpose_bf16<<<dim3(32, 32), 256, 0, stream>>>(wq, wqT, 1024, 1024, 1024);
    transpose_bf16<<<dim3(32, 32), 256, 0, stream>>>(wk, wkT, 1024, 1024, 1024);
    transpose_bf16<<<dim3(32, 32), 256, 0, stream>>>(wv, wvT, 1024, 1024, 1024);
    transpose_bf16<<<dim3(64, 32), 256, 0, stream>>>(w1, w1T, 2048, 1024, 1024);
    transpose_bf16<<<dim3(32, 4), 256, 0, stream>>>(w2, w2T, 1024, 100, 128);

    // k = enc*wk + bk   (8192x1024)
    gemm(encb, 0, 0, 1024, wkT, 0, 0, 1024, (float*)0, 0, 0, 0,
         kbf, 0, 0, 1024, bk, (const float*)0, 8192, 1024, 1024, 1, 0, 1);
    // vT[b][d][j] = (enc[b]*wv + bv)^T   (Z=16)
    gemm(wvT, 0, 0, 1024, encb, (long)512 * 1024, 0, 1024, (float*)0, 0, 0, 0,
         vT, (long)1024 * 512, 0, 512, (const float*)0, bv, 1024, 512, 1024, 1, 0, 16);
    // xg0 = emb*wih0^T + (bih0+bhh0)
    gemm(embb, 0, 0, 1024, wih0b, 0, 0, 1024, xg0, 0, 0, 4096,
         (bf16*)0, 0, 0, 0, bias0, (const float*)0, BT_, 4096, 1024, 1, 0, 1);

    // recurrence (wavefront over 2 layers)
    for (int s = 0; s <= 241; s++)
        lstm_step<<<128, 256, 0, stream>>>(whh0b, w1pk, xg0, bias1f, h0buf, A1buf,
                                           c0, c1, featsA, s);

    // q = h1*wq + bq
    gemm(featsA, 0, 0, 2048, wqT, 0, 0, 1024, (float*)0, 0, 0, 0,
         qbf, 0, 0, 1024, bq, (const float*)0, BT_, 1024, 1024, 1, 0, 1);
    // scores (raw) into d_out attn region, Z = 64 (b,h)
    float* attnOut = (float*)d_out + OUT0_;
    gemm(qbf, (long)241 * 1024, 256, 1024, kbf, (long)512 * 1024, 256, 1024,
         attnOut, (long)4 * 241 * 512, (long)241 * 512, 512,
         (bf16*)0, 0, 0, 0, (const float*)0, (const float*)0, 241, 512, 256, 4, 0, 64);
    attn_softmax<<<3856, 256, 0, stream>>>(attnOut, attnb, 15424);
    // ctx = attn*v -> ctx_f32 and featsA[:,1024:]
    gemm(attnb, (long)4 * 241 * 512, (long)241 * 512, 512,
         vT, (long)1024 * 512, (long)256 * 512, 512,
         ctxf, (long)241 * 1024, 256, 1024,
         featsA + 1024, (long)241 * 2048, 256, 2048,
         (const float*)0, (const float*)0, 241, 256, 512, 4, 0, 64);
    // x = tanh(feats*w1 + b1)
    gemm(featsA, 0, 0, 2048, w1T, 0, 0, 2048, (float*)0, 0, 0, 0,
         xbf, 0, 0, 1024, b1, (const float*)0, BT_, 1024, 2048, 1, 1, 1);
    // logits -> d_out[0:385600]
    gemm(xbf, 0, 0, 1024, w2T, 0, 0, 1024, (float*)d_out, 0, 0, 100,
         (bf16*)0, 0, 0, 0, b2, (const float*)0, BT_, 100, 1024, 1, 0, 1);
    logsoftmax_k<<<964, 256, 0, stream>>>((float*)d_out, BT_);

    long wn = (long)out_size - OUT0_ - OUT1_;
    if (wn > 0)
        words_fill<<<2048, 256, 0, stream>>>(meta, targets, embw, ctxf,
                                             (float*)d_out + OUT0_ + OUT1_, wn);
}

// Round 2
// 5166.790 us; speedup vs baseline: 1.0058x; 1.0058x over previous
//
#include <hip/hip_runtime.h>
#include <hip/hip_bf16.h>

typedef __bf16 bf16;
typedef __bf16 bf16x8 __attribute__((ext_vector_type(8)));
typedef float f32x4 __attribute__((ext_vector_type(4)));

#define B_ 16
#define T_ 241
#define H_ 1024
#define NC_ 100
#define TE_ 512
#define BT_ 3856   // B_*T_
#define OUT0_ 385600
#define OUT1_ 7897088
#define SEGCAP_ 3872

// ---------------- utility kernels ----------------

__global__ void zero_fill(unsigned* __restrict__ p, long n) {
    for (long i = (long)blockIdx.x * blockDim.x + threadIdx.x; i < n;
         i += (long)gridDim.x * blockDim.x) p[i] = 0u;
}

__global__ void bias_sum(const float* a0, const float* b0, const float* a1,
                         const float* b1, float* o0, float* o1) {
    int i = blockIdx.x * blockDim.x + threadIdx.x;
    if (i < 4096) { o0[i] = a0[i] + b0[i]; o1[i] = a1[i] + b1[i]; }
}

__global__ void f2bf(const float* __restrict__ in, bf16* __restrict__ out, long n) {
    for (long i = (long)blockIdx.x * blockDim.x + threadIdx.x; i < n;
         i += (long)gridDim.x * blockDim.x) out[i] = (bf16)in[i];
}

__global__ void embed_gather(const int* __restrict__ tg, const float* __restrict__ embw,
                             bf16* __restrict__ out, long n) {
    for (long i = (long)blockIdx.x * blockDim.x + threadIdx.x; i < n;
         i += (long)gridDim.x * blockDim.x) {
        int bt = (int)(i >> 10), d = (int)(i & 1023);
        out[i] = (bf16)embw[(long)tg[bt] * H_ + d];
    }
}

__global__ void pack_w1(const float* __restrict__ wih, const float* __restrict__ whh,
                        bf16* __restrict__ out) {
    long n = (long)4096 * 2048;
    for (long i = (long)blockIdx.x * blockDim.x + threadIdx.x; i < n;
         i += (long)gridDim.x * blockDim.x) {
        int r = (int)(i >> 11), k = (int)(i & 2047);
        float v = (k < 1024) ? wih[(long)r * 1024 + k] : whh[(long)r * 1024 + (k - 1024)];
        out[i] = (bf16)v;
    }
}

// out[n][k] = in[k][n], n < Cp (zero pad beyond C)
__global__ void transpose_bf16(const float* __restrict__ in, bf16* __restrict__ out,
                               int R, int C, int Cp) {
    __shared__ float tile[32][33];
    int k0 = blockIdx.x * 32, n0 = blockIdx.y * 32;
    int tx = threadIdx.x & 31, ty = threadIdx.x >> 5;  // 32x8
    for (int yy = ty; yy < 32; yy += 8) {
        int k = k0 + yy, n = n0 + tx;
        tile[yy][tx] = (k < R && n < C) ? in[(long)k * C + n] : 0.f;
    }
    __syncthreads();
    for (int yy = ty; yy < 32; yy += 8) {
        int n = n0 + yy, k = k0 + tx;
        if (n < Cp && k < R) out[(long)n * R + k] = (bf16)tile[tx][yy];
    }
}

// ---------------- generic A(row-major bf16) x Bt(row-major bf16) GEMM ----------------

struct GemmArgs {
    const bf16* A; long sAb; long sAh; int lda;
    const bf16* Bt; long sBb; long sBh; int ldb;
    float* C; long sCb; long sCh; int ldc;
    bf16* Cb; long sCbb; long sCbh; int ldcb;
    const float* biasCol; const float* biasRow;
    int M; int N; int K; int nh; int act;
};

__global__ void __launch_bounds__(256) gemm_bt(GemmArgs g) {
    int z = blockIdx.z;
    int zb = z / g.nh, zh = z - zb * g.nh;
    const bf16* A  = g.A  + (long)zb * g.sAb + (long)zh * g.sAh;
    const bf16* Bt = g.Bt + (long)zb * g.sBb + (long)zh * g.sBh;
    int wave = threadIdx.x >> 6, lane = threadIdx.x & 63;
    int l15 = lane & 15, kb = (lane >> 4) * 8;
    int mt0 = blockIdx.y * 4 + (wave >> 1) * 2;
    int ct0 = blockIdx.x * 4 + (wave & 1) * 2;
    const bf16* pa0 = A + (long)(mt0 * 16 + l15) * g.lda + kb;
    const bf16* pa1 = pa0 + (long)16 * g.lda;
    const bf16* pb0 = Bt + (long)(ct0 * 16 + l15) * g.ldb + kb;
    const bf16* pb1 = pb0 + (long)16 * g.ldb;
    f32x4 acc00 = {0.f,0.f,0.f,0.f}, acc01 = {0.f,0.f,0.f,0.f};
    f32x4 acc10 = {0.f,0.f,0.f,0.f}, acc11 = {0.f,0.f,0.f,0.f};
    for (int k = 0; k < g.K; k += 32) {
        bf16x8 a0 = *(const bf16x8*)(pa0 + k);
        bf16x8 a1 = *(const bf16x8*)(pa1 + k);
        bf16x8 b0 = *(const bf16x8*)(pb0 + k);
        bf16x8 b1 = *(const bf16x8*)(pb1 + k);
        acc00 = __builtin_amdgcn_mfma_f32_16x16x32_bf16(a0, b0, acc00, 0, 0, 0);
        acc01 = __builtin_amdgcn_mfma_f32_16x16x32_bf16(a0, b1, acc01, 0, 0, 0);
        acc10 = __builtin_amdgcn_mfma_f32_16x16x32_bf16(a1, b0, acc10, 0, 0, 0);
        acc11 = __builtin_amdgcn_mfma_f32_16x16x32_bf16(a1, b1, acc11, 0, 0, 0);
    }
    float* C  = g.C  ? g.C  + (long)zb * g.sCb  + (long)zh * g.sCh  : (float*)0;
    bf16*  Cb = g.Cb ? g.Cb + (long)zb * g.sCbb + (long)zh * g.sCbh : (bf16*)0;
    int rbase = (lane >> 4) * 4;
#pragma unroll
    for (int i = 0; i < 2; i++) {
#pragma unroll
        for (int j = 0; j < 2; j++) {
            f32x4 av = i ? (j ? acc11 : acc10) : (j ? acc01 : acc00);
            int colg = (ct0 + j) * 16 + l15;
            if (colg >= g.N) continue;
            float bc = g.biasCol ? g.biasCol[colg] : 0.f;
#pragma unroll
            for (int r = 0; r < 4; r++) {
                int rowg = (mt0 + i) * 16 + rbase + r;
                if (rowg >= g.M) continue;
                float val = av[r] + bc;
                if (g.biasRow) val += g.biasRow[rowg];
                if (g.act == 1) val = tanhf(val);
                if (C)  C[(long)rowg * g.ldc + colg] = val;
                if (Cb) Cb[(long)rowg * g.ldcb + colg] = (bf16)val;
            }
        }
    }
}

// ---------------- persistent LSTM recurrence ----------------
// 256 blocks: 0..127 layer0 (8 units each), 128..255 layer1.
// Weights live in VGPRs; cell state c lives in registers of the pointwise
// threads; h is exchanged through global memory with a device-scope barrier.

__device__ __forceinline__ void grid_barrier(unsigned* cnt, unsigned* epoch, unsigned nblk) {
    __syncthreads();
    if (threadIdx.x == 0) {
        unsigned e = __hip_atomic_load(epoch, __ATOMIC_RELAXED, __HIP_MEMORY_SCOPE_AGENT);
        unsigned arr = __hip_atomic_fetch_add(cnt, 1u, __ATOMIC_ACQ_REL, __HIP_MEMORY_SCOPE_AGENT);
        if (arr == nblk - 1) {
            __hip_atomic_store(cnt, 0u, __ATOMIC_RELAXED, __HIP_MEMORY_SCOPE_AGENT);
            __hip_atomic_store(epoch, e + 1u, __ATOMIC_RELEASE, __HIP_MEMORY_SCOPE_AGENT);
        } else {
            while (__hip_atomic_load(epoch, __ATOMIC_RELAXED, __HIP_MEMORY_SCOPE_AGENT) == e)
                __builtin_amdgcn_s_sleep(1);
            (void)__hip_atomic_load(epoch, __ATOMIC_ACQUIRE, __HIP_MEMORY_SCOPE_AGENT);
        }
    }
    __syncthreads();
}

__global__ void __launch_bounds__(256, 1) lstm_persist(
    const bf16* __restrict__ Whh0, const bf16* __restrict__ W1pk,
    const float* __restrict__ xg0, const float* __restrict__ bias1,
    bf16* __restrict__ h0buf, bf16* __restrict__ A1buf,
    bf16* __restrict__ featsA, unsigned* __restrict__ bar) {
    int blk = blockIdx.x;
    bool isL1 = blk >= 128;
    int bL = isL1 ? blk - 128 : blk;
    int ub = bL * 8;                          // first hidden unit of this block
    int wave = threadIdx.x >> 6, lane = threadIdx.x & 63;
    int l15 = lane & 15, kb = (lane >> 4) * 8;
    int rl0 = l15, rl1 = 16 + l15;            // local gate rows (2 col tiles)
    int grow0 = (rl0 >> 3) * 1024 + ub + (rl0 & 7);
    int grow1 = (rl1 >> 3) * 1024 + ub + (rl1 & 7);

    __shared__ float red[4][32][17];

    int pb = threadIdx.x >> 3, pj = threadIdx.x & 7;  // pointwise (batch, unit) tid<128
    int ug = ub + pj;
    float c_reg = 0.f;
    int rb = (lane >> 4) * 4;

    if (!isL1) {
        bf16x8 wa[8], wb[8];
        const bf16* p0 = Whh0 + (long)grow0 * 1024 + wave * 256 + kb;
        const bf16* p1 = Whh0 + (long)grow1 * 1024 + wave * 256 + kb;
#pragma unroll
        for (int i = 0; i < 8; i++) {
            wa[i] = *(const bf16x8*)(p0 + 32 * i);
            wb[i] = *(const bf16x8*)(p1 + 32 * i);
        }
        for (int s = 0; s <= 241; s++) {
            bool active = (s < 241);
            if (active) {
                f32x4 acc0 = {0.f,0.f,0.f,0.f}, acc1 = {0.f,0.f,0.f,0.f};
                const bf16* pa = h0buf + ((s & 1) << 14) + l15 * 1024 + wave * 256 + kb;
#pragma unroll
                for (int i = 0; i < 8; i++) {
                    bf16x8 a = *(const bf16x8*)(pa + 32 * i);
                    acc0 = __builtin_amdgcn_mfma_f32_16x16x32_bf16(a, wa[i], acc0, 0, 0, 0);
                    acc1 = __builtin_amdgcn_mfma_f32_16x16x32_bf16(a, wb[i], acc1, 0, 0, 0);
                }
#pragma unroll
                for (int r = 0; r < 4; r++) {
                    red[wave][rl0][rb + r] = acc0[r];
                    red[wave][rl1][rb + r] = acc1[r];
                }
            }
            __syncthreads();
            if (active && threadIdx.x < 128) {
                float g0 = 0.f, g1 = 0.f, g2 = 0.f, g3 = 0.f;
#pragma unroll
                for (int w = 0; w < 4; w++) {
                    g0 += red[w][pj][pb];      g1 += red[w][8 + pj][pb];
                    g2 += red[w][16 + pj][pb]; g3 += red[w][24 + pj][pb];
                }
                const float* xp = xg0 + ((long)pb * 241 + s) * 4096 + ug;
                g0 += xp[0]; g1 += xp[1024]; g2 += xp[2048]; g3 += xp[3072];
                float si = 1.f / (1.f + expf(-g0));
                float sf = 1.f / (1.f + expf(-g1));
                float so = 1.f / (1.f + expf(-g3));
                c_reg = sf * c_reg + si * tanhf(g2);
                float hv = so * tanhf(c_reg);
                int pn = (s + 1) & 1;
                h0buf[(pn << 14) + pb * 1024 + ug] = (bf16)hv;
                A1buf[(pn << 15) + pb * 2048 + ug] = (bf16)hv;
            }
            if (s < 241) grid_barrier(bar, bar + 1, 256);
        }
    } else {
        bf16x8 wa[16], wb[16];
        const bf16* p0 = W1pk + (long)grow0 * 2048 + wave * 512 + kb;
        const bf16* p1 = W1pk + (long)grow1 * 2048 + wave * 512 + kb;
#pragma unroll
        for (int i = 0; i < 16; i++) {
            wa[i] = *(const bf16x8*)(p0 + 32 * i);
            wb[i] = *(const bf16x8*)(p1 + 32 * i);
        }
        for (int s = 0; s <= 241; s++) {
            bool active = (s >= 1);
            if (active) {
                f32x4 acc0 = {0.f,0.f,0.f,0.f}, acc1 = {0.f,0.f,0.f,0.f};
                const bf16* pa = A1buf + ((s & 1) << 15) + l15 * 2048 + wave * 512 + kb;
#pragma unroll
                for (int i = 0; i < 16; i++) {
                    bf16x8 a = *(const bf16x8*)(pa + 32 * i);
                    acc0 = __builtin_amdgcn_mfma_f32_16x16x32_bf16(a, wa[i], acc0, 0, 0, 0);
                    acc1 = __builtin_amdgcn_mfma_f32_16x16x32_bf16(a, wb[i], acc1, 0, 0, 0);
                }
#pragma unroll
                for (int r = 0; r < 4; r++) {
                    red[wave][rl0][rb + r] = acc0[r];
                    red[wave][rl1][rb + r] = acc1[r];
                }
            }
            __syncthreads();
            if (active && threadIdx.x < 128) {
                float g0 = 0.f, g1 = 0.f, g2 = 0.f, g3 = 0.f;
#pragma unroll
                for (int w = 0; w < 4; w++) {
                    g0 += red[w][pj][pb];      g1 += red[w][8 + pj][pb];
                    g2 += red[w][16 + pj][pb]; g3 += red[w][24 + pj][pb];
                }
                g0 += bias1[ug]; g1 += bias1[1024 + ug];
                g2 += bias1[2048 + ug]; g3 += bias1[3072 + ug];
                float si = 1.f / (1.f + expf(-g0));
                float sf = 1.f / (1.f + expf(-g1));
                float so = 1.f / (1.f + expf(-g3));
                c_reg = sf * c_reg + si * tanhf(g2);
                float hv = so * tanhf(c_reg);
                int pn = (s + 1) & 1;
                A1buf[(pn << 15) + pb * 2048 + 1024 + ug] = (bf16)hv;
                featsA[((long)pb * 241 + (s - 1)) * 2048 + ug] = (bf16)hv;
            }
            if (s < 241) grid_barrier(bar, bar + 1, 256);
        }
    }
}

// ---------------- softmaxes ----------------

__global__ void __launch_bounds__(256) attn_softmax(float* __restrict__ attn,
                                                    bf16* __restrict__ attnb, int nrows) {
    int row = blockIdx.x * 4 + (threadIdx.x >> 6);
    int lane = threadIdx.x & 63;
    if (row >= nrows) return;
    float* p = attn + (long)row * 512;
    float v[8];
    float m = -1e30f;
#pragma unroll
    for (int j = 0; j < 8; j++) { v[j] = p[lane + 64 * j] * 0.0625f; m = fmaxf(m, v[j]); }
    for (int o = 32; o; o >>= 1) m = fmaxf(m, __shfl_xor(m, o));
    float ssum = 0.f;
#pragma unroll
    for (int j = 0; j < 8; j++) { v[j] = expf(v[j] - m); ssum += v[j]; }
    for (int o = 32; o; o >>= 1) ssum += __shfl_xor(ssum, o);
    float inv = 1.f / ssum;
#pragma unroll
    for (int j = 0; j < 8; j++) {
        float a = v[j] * inv;
        p[lane + 64 * j] = a;
        attnb[(long)row * 512 + lane + 64 * j] = (bf16)a;
    }
}

__global__ void __launch_bounds__(256) logsoftmax_k(float* __restrict__ out, int nrows) {
    int row = blockIdx.x * 4 + (threadIdx.x >> 6);
    int lane = threadIdx.x & 63;
    if (row >= nrows) return;
    float* p = out + (long)row * 100;
    float v0 = lane < 100 ? p[lane] : -1e30f;
    float v1 = lane < 36 ? p[64 + lane] : -1e30f;
    float m = fmaxf(v0, v1);
    for (int o = 32; o; o >>= 1) m = fmaxf(m, __shfl_xor(m, o));
    float s = (lane < 100 ? expf(v0 - m) : 0.f) + (lane < 36 ? expf(v1 - m) : 0.f);
    for (int o = 32; o; o >>= 1) s += __shfl_xor(s, o);
    float lg = m + logf(s);
    if (lane < 100) p[lane] = v0 - lg;
    if (lane < 36) p[64 + lane] = v1 - lg;
}

// ---------------- words ----------------

__global__ void seg_scan(const int* __restrict__ tg, int* __restrict__ meta) {
    __shared__ int st[16][242], ln[16][242];
    __shared__ int cnt[16], rmax[16], off[17];
    int b = threadIdx.x;
    if (b < 16) {
        const int* tok = tg + b * 241 + 1;
        int start = 0, n = 0, mx = 0; bool broke = false;
        for (int t = 0; t < 240; t++) {
            int v = tok[t];
            if (v == 1 || v == 2) {
                st[b][n] = start; ln[b][n] = t - start;
                if (t - start > mx) mx = t - start;
                n++; start = t + 1;
                if (v == 2) { broke = true; break; }
            }
        }
        if (!broke && start < 240) {
            st[b][n] = start; ln[b][n] = 240 - start;
            if (240 - start > mx) mx = 240 - start;
            n++;
        }
        cnt[b] = n; rmax[b] = mx;
    }
    __syncthreads();
    if (threadIdx.x == 0) {
        int tot = 0, mx = 0;
        for (int i = 0; i < 16; i++) { off[i] = tot; tot += cnt[i]; if (rmax[i] > mx) mx = rmax[i]; }
        off[16] = tot; meta[0] = tot; meta[1] = mx;
    }
    __syncthreads();
    if (b < 16) {
        int* segb = meta + 2; int* segs = segb + SEGCAP_; int* segl = segs + SEGCAP_;
        int o = off[b];
        for (int i = 0; i < cnt[b]; i++) { segb[o + i] = b; segs[o + i] = st[b][i]; segl[o + i] = ln[b][i]; }
    }
}

__global__ void words_fill(const int* __restrict__ meta, const int* __restrict__ tg,
                           const float* __restrict__ embw, const float* __restrict__ ctxf,
                           float* __restrict__ out2, long nelem) {
    int N = meta[0], mx = meta[1];
    const int* segb = meta + 2;
    const int* segs = segb + SEGCAP_;
    const int* segl = segs + SEGCAP_;
    unsigned wl = (unsigned)mx * 2048u;
    if (wl == 0) wl = 1u;
    for (long ee = (long)blockIdx.x * blockDim.x + threadIdx.x; ee < nelem;
         ee += (long)gridDim.x * blockDim.x) {
        unsigned e = (unsigned)ee;
        unsigned n = e / wl, rem = e - n * wl;
        unsigned l = rem >> 11, d = rem & 2047u;
        float val = 0.f;
        if ((int)n < N && (int)l < segl[n]) {
            int b = segb[n]; int tp = segs[n] + (int)l;  // index in sliced [0,240)
            if (d < 1024u) val = embw[(long)tg[b * 241 + tp + 1] * H_ + d];
            else val = ctxf[((long)b * 241 + tp) * H_ + (d - 1024u)];
        }
        out2[ee] = val;
    }
}

// ---------------- host ----------------

extern "C" void kernel_launch(void* const* d_in, const int* in_sizes, int n_in,
                              void* d_out, int out_size, void* d_ws, size_t ws_size,
                              hipStream_t stream) {
    const int*   targets = (const int*)d_in[0];
    const float* enc  = (const float*)d_in[1];
    const float* embw = (const float*)d_in[2];
    const float* wih0 = (const float*)d_in[3];
    const float* whh0 = (const float*)d_in[4];
    const float* bih0 = (const float*)d_in[5];
    const float* bhh0 = (const float*)d_in[6];
    const float* wih1 = (const float*)d_in[7];
    const float* whh1 = (const float*)d_in[8];
    const float* bih1 = (const float*)d_in[9];
    const float* bhh1 = (const float*)d_in[10];
    const float* wq = (const float*)d_in[11];
    const float* bq = (const float*)d_in[12];
    const float* wk = (const float*)d_in[13];
    const float* bk = (const float*)d_in[14];
    const float* wv = (const float*)d_in[15];
    const float* bv = (const float*)d_in[16];
    const float* w1 = (const float*)d_in[17];
    const float* b1 = (const float*)d_in[18];
    const float* w2 = (const float*)d_in[19];
    const float* b2 = (const float*)d_in[20];

    char* ws = (char*)d_ws;
    size_t off = 0;
    auto alloc = [&](size_t bytes) {
        char* p = ws + off; off += (bytes + 255) & ~(size_t)255; return p;
    };
    // state (zeroed each call; must stay contiguous: h0buf, A1buf, bar)
    bf16* h0buf = (bf16*)alloc(65536);
    bf16* A1buf = (bf16*)alloc(131072);
    unsigned* bar = (unsigned*)alloc(256);
    float* bias0 = (float*)alloc(16384);
    float* bias1f = (float*)alloc(16384);
    int* meta = (int*)alloc((2 + 3 * SEGCAP_) * 4);
    bf16* kbf = (bf16*)alloc((size_t)8192 * 1024 * 2);
    bf16* vT  = (bf16*)alloc((size_t)16 * 1024 * 512 * 2);
    bf16* wqT = (bf16*)alloc((size_t)1024 * 1024 * 2);
    bf16* w1T = (bf16*)alloc((size_t)1024 * 2048 * 2);
    bf16* w2T = (bf16*)alloc((size_t)128 * 1024 * 2);
    bf16* featsA = (bf16*)alloc((size_t)3920 * 2048 * 2);
    char* regB = alloc(63176704);              // xg0; reused after recurrence
    float* xg0  = (float*)regB;
    bf16* qbf   = (bf16*)regB;                           // 3920*1024*2 = 8028160
    bf16* attnb = (bf16*)(regB + 8028160);               // 15488*512*2 = 15859712
    float* ctxf = (float*)(regB + 8028160 + 15859712);   // 3856*1024*4 = 15794176
    bf16* xbf   = (bf16*)(regB + 39682048);              // 3920*1024*2
    bf16* embb  = (bf16*)alloc((size_t)3920 * 1024 * 2);
    bf16* encb  = (bf16*)alloc((size_t)8192 * 1024 * 2);
    bf16* wih0b = (bf16*)alloc((size_t)4096 * 1024 * 2);
    bf16* whh0b = (bf16*)alloc((size_t)4096 * 1024 * 2);
    bf16* w1pk  = (bf16*)alloc((size_t)4096 * 2048 * 2);
    bf16* wkT = (bf16*)alloc((size_t)1024 * 1024 * 2);
    bf16* wvT = (bf16*)alloc((size_t)1024 * 1024 * 2);
    (void)ws_size; (void)in_sizes; (void)n_in;

    auto gemm = [&](const bf16* A, long sAb, long sAh, int lda,
                    const bf16* Bt, long sBb, long sBh, int ldb,
                    float* C, long sCb, long sCh, int ldc,
                    bf16* Cb, long sCbb, long sCbh, int ldcb,
                    const float* bc, const float* br,
                    int M, int N, int K, int nh, int act, int Z) {
        GemmArgs ga{A, sAb, sAh, lda, Bt, sBb, sBh, ldb, C, sCb, sCh, ldc,
                    Cb, sCbb, sCbh, ldcb, bc, br, M, N, K, nh, act};
        dim3 grid((N + 63) / 64, (M + 63) / 64, Z);
        gemm_bt<<<grid, 256, 0, stream>>>(ga);
    };

    // prep
    zero_fill<<<64, 256, 0, stream>>>((unsigned*)h0buf, 49216);
    bias_sum<<<16, 256, 0, stream>>>(bih0, bhh0, bih1, bhh1, bias0, bias1f);
    seg_scan<<<1, 64, 0, stream>>>(targets, meta);
    embed_gather<<<2048, 256, 0, stream>>>(targets, embw, embb, (long)BT_ * 1024);
    f2bf<<<2048, 256, 0, stream>>>(enc, encb, (long)8192 * 1024);
    f2bf<<<2048, 256, 0, stream>>>(wih0, wih0b, (long)4096 * 1024);
    f2bf<<<2048, 256, 0, stream>>>(whh0, whh0b, (long)4096 * 1024);
    pack_w1<<<2048, 256, 0, stream>>>(wih1, whh1, w1pk);
    transpose_bf16<<<dim3(32, 32), 256, 0, stream>>>(wq, wqT, 1024, 1024, 1024);
    transpose_bf16<<<dim3(32, 32), 256, 0, stream>>>(wk, wkT, 1024, 1024, 1024);
    transpose_bf16<<<dim3(32, 32), 256, 0, stream>>>(wv, wvT, 1024, 1024, 1024);
    transpose_bf16<<<dim3(64, 32), 256, 0, stream>>>(w1, w1T, 2048, 1024, 1024);
    transpose_bf16<<<dim3(32, 4), 256, 0, stream>>>(w2, w2T, 1024, 100, 128);

    // k = enc*wk + bk   (8192x1024)
    gemm(encb, 0, 0, 1024, wkT, 0, 0, 1024, (float*)0, 0, 0, 0,
         kbf, 0, 0, 1024, bk, (const float*)0, 8192, 1024, 1024, 1, 0, 1);
    // vT[b][d][j] = (enc[b]*wv + bv)^T   (Z=16)
    gemm(wvT, 0, 0, 1024, encb, (long)512 * 1024, 0, 1024, (float*)0, 0, 0, 0,
         vT, (long)1024 * 512, 0, 512, (const float*)0, bv, 1024, 512, 1024, 1, 0, 16);
    // xg0 = emb*wih0^T + (bih0+bhh0)
    gemm(embb, 0, 0, 1024, wih0b, 0, 0, 1024, xg0, 0, 0, 4096,
         (bf16*)0, 0, 0, 0, bias0, (const float*)0, BT_, 4096, 1024, 1, 0, 1);

    // recurrence: one persistent kernel, 242 wavefront iterations
    lstm_persist<<<256, 256, 0, stream>>>(whh0b, w1pk, xg0, bias1f,
                                          h0buf, A1buf, featsA, bar);

    // q = h1*wq + bq
    gemm(featsA, 0, 0, 2048, wqT, 0, 0, 1024, (float*)0, 0, 0, 0,
         qbf, 0, 0, 1024, bq, (const float*)0, BT_, 1024, 1024, 1, 0, 1);
    // scores (raw) into d_out attn region, Z = 64 (b,h)
    float* attnOut = (float*)d_out + OUT0_;
    gemm(qbf, (long)241 * 1024, 256, 1024, kbf, (long)512 * 1024, 256, 1024,
         attnOut, (long)4 * 241 * 512, (long)241 * 512, 512,
         (bf16*)0, 0, 0, 0, (const float*)0, (const float*)0, 241, 512, 256, 4, 0, 64);
    attn_softmax<<<3856, 256, 0, stream>>>(attnOut, attnb, 15424);
    // ctx = attn*v -> ctx_f32 and featsA[:,1024:]
    gemm(attnb, (long)4 * 241 * 512, (long)241 * 512, 512,
         vT, (long)1024 * 512, (long)256 * 512, 512,
         ctxf, (long)241 * 1024, 256, 1024,
         featsA + 1024, (long)241 * 2048, 256, 2048,
         (const float*)0, (const float*)0, 241, 256, 512, 4, 0, 64);
    // x = tanh(feats*w1 + b1)
    gemm(featsA, 0, 0, 2048, w1T, 0, 0, 2048, (float*)0, 0, 0, 0,
         xbf, 0, 0, 1024, b1, (const float*)0, BT_, 1024, 2048, 1, 1, 1);
    // logits -> d_out[0:385600]
    gemm(xbf, 0, 0, 1024, w2T, 0, 0, 1024, (float*)d_out, 0, 0, 100,
         (bf16*)0, 0, 0, 0, b2, (const float*)0, BT_, 100, 1024, 1, 0, 1);
    logsoftmax_k<<<964, 256, 0, stream>>>((float*)d_out, BT_);

    long wn = (long)out_size - OUT0_ - OUT1_;
    if (wn > 0)
        words_fill<<<2048, 256, 0, stream>>>(meta, targets, embw, ctxf,
                                             (float*)d_out + OUT0_ + OUT1_, wn);
}

// Round 3
// 2683.479 us; speedup vs baseline: 1.9366x; 1.9254x over previous
//
#include <hip/hip_runtime.h>
#include <hip/hip_bf16.h>

typedef __bf16 bf16;
typedef __bf16 bf16x8 __attribute__((ext_vector_type(8)));
typedef float f32x4 __attribute__((ext_vector_type(4)));
typedef unsigned long long u64;
typedef u64 u64x2 __attribute__((ext_vector_type(2)));

#define B_ 16
#define T_ 241
#define H_ 1024
#define NC_ 100
#define TE_ 512
#define BT_ 3856   // B_*T_
#define OUT0_ 385600
#define OUT1_ 7897088
#define SEGCAP_ 3872

// ---------------- utility kernels ----------------

__global__ void zero_fill(unsigned* __restrict__ p, long n) {
    for (long i = (long)blockIdx.x * blockDim.x + threadIdx.x; i < n;
         i += (long)gridDim.x * blockDim.x) p[i] = 0u;
}

__global__ void bias_sum(const float* a0, const float* b0, const float* a1,
                         const float* b1, float* o0, float* o1) {
    int i = blockIdx.x * blockDim.x + threadIdx.x;
    if (i < 4096) { o0[i] = a0[i] + b0[i]; o1[i] = a1[i] + b1[i]; }
}

__global__ void f2bf(const float* __restrict__ in, bf16* __restrict__ out, long n) {
    for (long i = (long)blockIdx.x * blockDim.x + threadIdx.x; i < n;
         i += (long)gridDim.x * blockDim.x) out[i] = (bf16)in[i];
}

__global__ void embed_gather(const int* __restrict__ tg, const float* __restrict__ embw,
                             bf16* __restrict__ out, long n) {
    for (long i = (long)blockIdx.x * blockDim.x + threadIdx.x; i < n;
         i += (long)gridDim.x * blockDim.x) {
        int bt = (int)(i >> 10), d = (int)(i & 1023);
        out[i] = (bf16)embw[(long)tg[bt] * H_ + d];
    }
}

__global__ void pack_w1(const float* __restrict__ wih, const float* __restrict__ whh,
                        bf16* __restrict__ out) {
    long n = (long)4096 * 2048;
    for (long i = (long)blockIdx.x * blockDim.x + threadIdx.x; i < n;
         i += (long)gridDim.x * blockDim.x) {
        int r = (int)(i >> 11), k = (int)(i & 2047);
        float v = (k < 1024) ? wih[(long)r * 1024 + k] : whh[(long)r * 1024 + (k - 1024)];
        out[i] = (bf16)v;
    }
}

// out[n][k] = in[k][n], n < Cp (zero pad beyond C)
__global__ void transpose_bf16(const float* __restrict__ in, bf16* __restrict__ out,
                               int R, int C, int Cp) {
    __shared__ float tile[32][33];
    int k0 = blockIdx.x * 32, n0 = blockIdx.y * 32;
    int tx = threadIdx.x & 31, ty = threadIdx.x >> 5;  // 32x8
    for (int yy = ty; yy < 32; yy += 8) {
        int k = k0 + yy, n = n0 + tx;
        tile[yy][tx] = (k < R && n < C) ? in[(long)k * C + n] : 0.f;
    }
    __syncthreads();
    for (int yy = ty; yy < 32; yy += 8) {
        int n = n0 + yy, k = k0 + tx;
        if (n < Cp && k < R) out[(long)n * R + k] = (bf16)tile[tx][yy];
    }
}

// ---------------- generic A(row-major bf16) x Bt(row-major bf16) GEMM ----------------

struct GemmArgs {
    const bf16* A; long sAb; long sAh; int lda;
    const bf16* Bt; long sBb; long sBh; int ldb;
    float* C; long sCb; long sCh; int ldc;
    bf16* Cb; long sCbb; long sCbh; int ldcb;
    const float* biasCol; const float* biasRow;
    int M; int N; int K; int nh; int act;
};

__global__ void __launch_bounds__(256) gemm_bt(GemmArgs g) {
    int z = blockIdx.z;
    int zb = z / g.nh, zh = z - zb * g.nh;
    const bf16* A  = g.A  + (long)zb * g.sAb + (long)zh * g.sAh;
    const bf16* Bt = g.Bt + (long)zb * g.sBb + (long)zh * g.sBh;
    int wave = threadIdx.x >> 6, lane = threadIdx.x & 63;
    int l15 = lane & 15, kb = (lane >> 4) * 8;
    int mt0 = blockIdx.y * 4 + (wave >> 1) * 2;
    int ct0 = blockIdx.x * 4 + (wave & 1) * 2;
    const bf16* pa0 = A + (long)(mt0 * 16 + l15) * g.lda + kb;
    const bf16* pa1 = pa0 + (long)16 * g.lda;
    const bf16* pb0 = Bt + (long)(ct0 * 16 + l15) * g.ldb + kb;
    const bf16* pb1 = pb0 + (long)16 * g.ldb;
    f32x4 acc00 = {0.f,0.f,0.f,0.f}, acc01 = {0.f,0.f,0.f,0.f};
    f32x4 acc10 = {0.f,0.f,0.f,0.f}, acc11 = {0.f,0.f,0.f,0.f};
    for (int k = 0; k < g.K; k += 32) {
        bf16x8 a0 = *(const bf16x8*)(pa0 + k);
        bf16x8 a1 = *(const bf16x8*)(pa1 + k);
        bf16x8 b0 = *(const bf16x8*)(pb0 + k);
        bf16x8 b1 = *(const bf16x8*)(pb1 + k);
        acc00 = __builtin_amdgcn_mfma_f32_16x16x32_bf16(a0, b0, acc00, 0, 0, 0);
        acc01 = __builtin_amdgcn_mfma_f32_16x16x32_bf16(a0, b1, acc01, 0, 0, 0);
        acc10 = __builtin_amdgcn_mfma_f32_16x16x32_bf16(a1, b0, acc10, 0, 0, 0);
        acc11 = __builtin_amdgcn_mfma_f32_16x16x32_bf16(a1, b1, acc11, 0, 0, 0);
    }
    float* C  = g.C  ? g.C  + (long)zb * g.sCb  + (long)zh * g.sCh  : (float*)0;
    bf16*  Cb = g.Cb ? g.Cb + (long)zb * g.sCbb + (long)zh * g.sCbh : (bf16*)0;
    int rbase = (lane >> 4) * 4;
#pragma unroll
    for (int i = 0; i < 2; i++) {
#pragma unroll
        for (int j = 0; j < 2; j++) {
            f32x4 av = i ? (j ? acc11 : acc10) : (j ? acc01 : acc00);
            int colg = (ct0 + j) * 16 + l15;
            if (colg >= g.N) continue;
            float bc = g.biasCol ? g.biasCol[colg] : 0.f;
#pragma unroll
            for (int r = 0; r < 4; r++) {
                int rowg = (mt0 + i) * 16 + rbase + r;
                if (rowg >= g.M) continue;
                float val = av[r] + bc;
                if (g.biasRow) val += g.biasRow[rowg];
                if (g.act == 1) val = tanhf(val);
                if (C)  C[(long)rowg * g.ldc + colg] = val;
                if (Cb) Cb[(long)rowg * g.ldcb + colg] = (bf16)val;
            }
        }
    }
}

// ---------------- persistent LSTM recurrence ----------------
// 256 blocks: 0..127 layer0 (8 units each), 128..255 layer1.
// Weights pinned in VGPRs; cell state in registers; h exchanged through the
// coherent point (L3) with relaxed agent-scope atomics; flag-array barrier
// (no RMW contention, no L2 writeback/invalidate fences).

__device__ __forceinline__ u64 cload(const u64* p) {
    return __hip_atomic_load(p, __ATOMIC_RELAXED, __HIP_MEMORY_SCOPE_AGENT);
}
__device__ __forceinline__ void cstore(unsigned* p, unsigned v) {
    __hip_atomic_store(p, v, __ATOMIC_RELAXED, __HIP_MEMORY_SCOPE_AGENT);
}
__device__ __forceinline__ unsigned pack2(bf16 a, bf16 b) {
    union { bf16 h[2]; unsigned u; } x; x.h[0] = a; x.h[1] = b; return x.u;
}

__global__ void __launch_bounds__(256, 1) lstm_persist(
    const bf16* __restrict__ Whh0, const bf16* __restrict__ W1pk,
    const float* __restrict__ xg0, const float* __restrict__ bias1,
    bf16* __restrict__ h0buf, bf16* __restrict__ A1buf,
    bf16* __restrict__ featsA, unsigned* __restrict__ flags) {
    int blk = blockIdx.x;
    bool isL1 = blk >= 128;
    int bL = isL1 ? blk - 128 : blk;
    int ub = bL * 8;                          // first hidden unit of this block
    int wave = threadIdx.x >> 6, lane = threadIdx.x & 63;
    int l15 = lane & 15, kb = (lane >> 4) * 8;
    int rl0 = l15, rl1 = 16 + l15;            // local gate rows (2 col tiles)
    int grow0 = (rl0 >> 3) * 1024 + ub + (rl0 & 7);
    int grow1 = (rl1 >> 3) * 1024 + ub + (rl1 & 7);

    __shared__ float red[4][32][17];

    int t = threadIdx.x;
    int pb = t >> 2, up = (t & 3) * 2;        // pointwise: 64 threads, 2 units each
    float cr0 = 0.f, cr1 = 0.f;
    int rb = (lane >> 4) * 4;

    if (!isL1) {
        f32x4 wa[8], wb[8];
        const bf16* p0 = Whh0 + (long)grow0 * 1024 + wave * 256 + kb;
        const bf16* p1 = Whh0 + (long)grow1 * 1024 + wave * 256 + kb;
#pragma unroll
        for (int i = 0; i < 8; i++) {
            wa[i] = *(const f32x4*)(p0 + 32 * i);
            wb[i] = *(const f32x4*)(p1 + 32 * i);
            asm volatile("" : "+v"(wa[i]), "+v"(wb[i]));
        }
        for (int s = 0; s <= 241; s++) {
            bool active = (s < 241);
            if (active) {
                f32x4 acc0 = {0.f,0.f,0.f,0.f}, acc1 = {0.f,0.f,0.f,0.f};
                const bf16* pa = h0buf + ((s & 1) << 14) + l15 * 1024 + wave * 256 + kb;
                u64x2 hf[8];
#pragma unroll
                for (int i = 0; i < 8; i++) {
                    const u64* q = (const u64*)(pa + 32 * i);
                    hf[i].x = cload(q); hf[i].y = cload(q + 1);
                }
#pragma unroll
                for (int i = 0; i < 8; i++) {
                    bf16x8 a = __builtin_bit_cast(bf16x8, hf[i]);
                    acc0 = __builtin_amdgcn_mfma_f32_16x16x32_bf16(a, __builtin_bit_cast(bf16x8, wa[i]), acc0, 0, 0, 0);
                    acc1 = __builtin_amdgcn_mfma_f32_16x16x32_bf16(a, __builtin_bit_cast(bf16x8, wb[i]), acc1, 0, 0, 0);
                }
#pragma unroll
                for (int r = 0; r < 4; r++) {
                    red[wave][rl0][rb + r] = acc0[r];
                    red[wave][rl1][rb + r] = acc1[r];
                }
            }
            __syncthreads();
            if (active && t < 64) {
                float g[2][4];
#pragma unroll
                for (int uu = 0; uu < 2; uu++)
#pragma unroll
                    for (int gi = 0; gi < 4; gi++) {
                        float v = 0.f;
#pragma unroll
                        for (int w = 0; w < 4; w++) v += red[w][gi * 8 + up + uu][pb];
                        g[uu][gi] = v;
                    }
                const float* xp = xg0 + ((long)pb * 241 + s) * 4096 + ub + up;
                bf16 hv[2];
#pragma unroll
                for (int uu = 0; uu < 2; uu++) {
                    float gi_ = g[uu][0] + xp[uu];
                    float gf_ = g[uu][1] + xp[1024 + uu];
                    float gg_ = g[uu][2] + xp[2048 + uu];
                    float go_ = g[uu][3] + xp[3072 + uu];
                    float si = 1.f / (1.f + expf(-gi_));
                    float sf = 1.f / (1.f + expf(-gf_));
                    float so = 1.f / (1.f + expf(-go_));
                    float& cr = uu ? cr1 : cr0;
                    cr = sf * cr + si * tanhf(gg_);
                    hv[uu] = (bf16)(so * tanhf(cr));
                }
                unsigned pv = pack2(hv[0], hv[1]);
                int pn = (s + 1) & 1;
                cstore((unsigned*)(h0buf + (pn << 14) + pb * 1024 + ub + up), pv);
                cstore((unsigned*)(A1buf + (pn << 15) + pb * 2048 + ub + up), pv);
            }
            if (s < 241) {
                __syncthreads();               // drains all waves' stores (vmcnt 0)
                unsigned tgt = (unsigned)(s + 1);
                if (t == 0) cstore(flags + blk * 4, tgt);
                while (__hip_atomic_load(flags + t * 4, __ATOMIC_RELAXED,
                                         __HIP_MEMORY_SCOPE_AGENT) < tgt)
                    __builtin_amdgcn_s_sleep(1);
                __syncthreads();
            }
        }
    } else {
        f32x4 wa[16], wb[16];
        const bf16* p0 = W1pk + (long)grow0 * 2048 + wave * 512 + kb;
        const bf16* p1 = W1pk + (long)grow1 * 2048 + wave * 512 + kb;
#pragma unroll
        for (int i = 0; i < 16; i++) {
            wa[i] = *(const f32x4*)(p0 + 32 * i);
            wb[i] = *(const f32x4*)(p1 + 32 * i);
            asm volatile("" : "+v"(wa[i]), "+v"(wb[i]));
        }
        for (int s = 0; s <= 241; s++) {
            bool active = (s >= 1);
            if (active) {
                f32x4 acc0 = {0.f,0.f,0.f,0.f}, acc1 = {0.f,0.f,0.f,0.f};
                const bf16* pa = A1buf + ((s & 1) << 15) + l15 * 2048 + wave * 512 + kb;
                u64x2 hf[16];
#pragma unroll
                for (int i = 0; i < 16; i++) {
                    const u64* q = (const u64*)(pa + 32 * i);
                    hf[i].x = cload(q); hf[i].y = cload(q + 1);
                }
#pragma unroll
                for (int i = 0; i < 16; i++) {
                    bf16x8 a = __builtin_bit_cast(bf16x8, hf[i]);
                    acc0 = __builtin_amdgcn_mfma_f32_16x16x32_bf16(a, __builtin_bit_cast(bf16x8, wa[i]), acc0, 0, 0, 0);
                    acc1 = __builtin_amdgcn_mfma_f32_16x16x32_bf16(a, __builtin_bit_cast(bf16x8, wb[i]), acc1, 0, 0, 0);
                }
#pragma unroll
                for (int r = 0; r < 4; r++) {
                    red[wave][rl0][rb + r] = acc0[r];
                    red[wave][rl1][rb + r] = acc1[r];
                }
            }
            __syncthreads();
            if (active && t < 64) {
                float g[2][4];
#pragma unroll
                for (int uu = 0; uu < 2; uu++)
#pragma unroll
                    for (int gi = 0; gi < 4; gi++) {
                        float v = 0.f;
#pragma unroll
                        for (int w = 0; w < 4; w++) v += red[w][gi * 8 + up + uu][pb];
                        g[uu][gi] = v;
                    }
                bf16 hv[2];
#pragma unroll
                for (int uu = 0; uu < 2; uu++) {
                    float gi_ = g[uu][0] + bias1[ub + up + uu];
                    float gf_ = g[uu][1] + bias1[1024 + ub + up + uu];
                    float gg_ = g[uu][2] + bias1[2048 + ub + up + uu];
                    float go_ = g[uu][3] + bias1[3072 + ub + up + uu];
                    float si = 1.f / (1.f + expf(-gi_));
                    float sf = 1.f / (1.f + expf(-gf_));
                    float so = 1.f / (1.f + expf(-go_));
                    float& cr = uu ? cr1 : cr0;
                    cr = sf * cr + si * tanhf(gg_);
                    hv[uu] = (bf16)(so * tanhf(cr));
                }
                unsigned pv = pack2(hv[0], hv[1]);
                int pn = (s + 1) & 1;
                cstore((unsigned*)(A1buf + (pn << 15) + pb * 2048 + 1024 + ub + up), pv);
                *(unsigned*)(featsA + ((long)pb * 241 + (s - 1)) * 2048 + ub + up) = pv;
            }
            if (s < 241) {
                __syncthreads();
                unsigned tgt = (unsigned)(s + 1);
                if (t == 0) cstore(flags + blk * 4, tgt);
                while (__hip_atomic_load(flags + t * 4, __ATOMIC_RELAXED,
                                         __HIP_MEMORY_SCOPE_AGENT) < tgt)
                    __builtin_amdgcn_s_sleep(1);
                __syncthreads();
            }
        }
    }
}

// ---------------- softmaxes ----------------

__global__ void __launch_bounds__(256) attn_softmax(float* __restrict__ attn,
                                                    bf16* __restrict__ attnb, int nrows) {
    int row = blockIdx.x * 4 + (threadIdx.x >> 6);
    int lane = threadIdx.x & 63;
    if (row >= nrows) return;
    float* p = attn + (long)row * 512;
    float v[8];
    float m = -1e30f;
#pragma unroll
    for (int j = 0; j < 8; j++) { v[j] = p[lane + 64 * j] * 0.0625f; m = fmaxf(m, v[j]); }
    for (int o = 32; o; o >>= 1) m = fmaxf(m, __shfl_xor(m, o));
    float ssum = 0.f;
#pragma unroll
    for (int j = 0; j < 8; j++) { v[j] = expf(v[j] - m); ssum += v[j]; }
    for (int o = 32; o; o >>= 1) ssum += __shfl_xor(ssum, o);
    float inv = 1.f / ssum;
#pragma unroll
    for (int j = 0; j < 8; j++) {
        float a = v[j] * inv;
        p[lane + 64 * j] = a;
        attnb[(long)row * 512 + lane + 64 * j] = (bf16)a;
    }
}

__global__ void __launch_bounds__(256) logsoftmax_k(float* __restrict__ out, int nrows) {
    int row = blockIdx.x * 4 + (threadIdx.x >> 6);
    int lane = threadIdx.x & 63;
    if (row >= nrows) return;
    float* p = out + (long)row * 100;
    float v0 = lane < 100 ? p[lane] : -1e30f;
    float v1 = lane < 36 ? p[64 + lane] : -1e30f;
    float m = fmaxf(v0, v1);
    for (int o = 32; o; o >>= 1) m = fmaxf(m, __shfl_xor(m, o));
    float s = (lane < 100 ? expf(v0 - m) : 0.f) + (lane < 36 ? expf(v1 - m) : 0.f);
    for (int o = 32; o; o >>= 1) s += __shfl_xor(s, o);
    float lg = m + logf(s);
    if (lane < 100) p[lane] = v0 - lg;
    if (lane < 36) p[64 + lane] = v1 - lg;
}

// ---------------- words ----------------

__global__ void seg_scan(const int* __restrict__ tg, int* __restrict__ meta) {
    __shared__ int st[16][242], ln[16][242];
    __shared__ int cnt[16], rmax[16], off[17];
    int b = threadIdx.x;
    if (b < 16) {
        const int* tok = tg + b * 241 + 1;
        int start = 0, n = 0, mx = 0; bool broke = false;
        for (int t = 0; t < 240; t++) {
            int v = tok[t];
            if (v == 1 || v == 2) {
                st[b][n] = start; ln[b][n] = t - start;
                if (t - start > mx) mx = t - start;
                n++; start = t + 1;
                if (v == 2) { broke = true; break; }
            }
        }
        if (!broke && start < 240) {
            st[b][n] = start; ln[b][n] = 240 - start;
            if (240 - start > mx) mx = 240 - start;
            n++;
        }
        cnt[b] = n; rmax[b] = mx;
    }
    __syncthreads();
    if (threadIdx.x == 0) {
        int tot = 0, mx = 0;
        for (int i = 0; i < 16; i++) { off[i] = tot; tot += cnt[i]; if (rmax[i] > mx) mx = rmax[i]; }
        off[16] = tot; meta[0] = tot; meta[1] = mx;
    }
    __syncthreads();
    if (b < 16) {
        int* segb = meta + 2; int* segs = segb + SEGCAP_; int* segl = segs + SEGCAP_;
        int o = off[b];
        for (int i = 0; i < cnt[b]; i++) { segb[o + i] = b; segs[o + i] = st[b][i]; segl[o + i] = ln[b][i]; }
    }
}

__global__ void words_fill(const int* __restrict__ meta, const int* __restrict__ tg,
                           const float* __restrict__ embw, const float* __restrict__ ctxf,
                           float* __restrict__ out2, long nelem) {
    int N = meta[0], mx = meta[1];
    const int* segb = meta + 2;
    const int* segs = segb + SEGCAP_;
    const int* segl = segs + SEGCAP_;
    unsigned wl = (unsigned)mx * 2048u;
    if (wl == 0) wl = 1u;
    for (long ee = (long)blockIdx.x * blockDim.x + threadIdx.x; ee < nelem;
         ee += (long)gridDim.x * blockDim.x) {
        unsigned e = (unsigned)ee;
        unsigned n = e / wl, rem = e - n * wl;
        unsigned l = rem >> 11, d = rem & 2047u;
        float val = 0.f;
        if ((int)n < N && (int)l < segl[n]) {
            int b = segb[n]; int tp = segs[n] + (int)l;  // index in sliced [0,240)
            if (d < 1024u) val = embw[(long)tg[b * 241 + tp + 1] * H_ + d];
            else val = ctxf[((long)b * 241 + tp) * H_ + (d - 1024u)];
        }
        out2[ee] = val;
    }
}

// ---------------- host ----------------

extern "C" void kernel_launch(void* const* d_in, const int* in_sizes, int n_in,
                              void* d_out, int out_size, void* d_ws, size_t ws_size,
                              hipStream_t stream) {
    const int*   targets = (const int*)d_in[0];
    const float* enc  = (const float*)d_in[1];
    const float* embw = (const float*)d_in[2];
    const float* wih0 = (const float*)d_in[3];
    const float* whh0 = (const float*)d_in[4];
    const float* bih0 = (const float*)d_in[5];
    const float* bhh0 = (const float*)d_in[6];
    const float* wih1 = (const float*)d_in[7];
    const float* whh1 = (const float*)d_in[8];
    const float* bih1 = (const float*)d_in[9];
    const float* bhh1 = (const float*)d_in[10];
    const float* wq = (const float*)d_in[11];
    const float* bq = (const float*)d_in[12];
    const float* wk = (const float*)d_in[13];
    const float* bk = (const float*)d_in[14];
    const float* wv = (const float*)d_in[15];
    const float* bv = (const float*)d_in[16];
    const float* w1 = (const float*)d_in[17];
    const float* b1 = (const float*)d_in[18];
    const float* w2 = (const float*)d_in[19];
    const float* b2 = (const float*)d_in[20];

    char* ws = (char*)d_ws;
    size_t off = 0;
    auto alloc = [&](size_t bytes) {
        char* p = ws + off; off += (bytes + 255) & ~(size_t)255; return p;
    };
    // state (zeroed each call; h0buf, A1buf, flags must stay contiguous)
    bf16* h0buf = (bf16*)alloc(65536);
    bf16* A1buf = (bf16*)alloc(131072);
    unsigned* flags = (unsigned*)alloc(4096);   // 256 flags, 16B stride
    float* bias0 = (float*)alloc(16384);
    float* bias1f = (float*)alloc(16384);
    int* meta = (int*)alloc((2 + 3 * SEGCAP_) * 4);
    bf16* kbf = (bf16*)alloc((size_t)8192 * 1024 * 2);
    bf16* vT  = (bf16*)alloc((size_t)16 * 1024 * 512 * 2);
    bf16* wqT = (bf16*)alloc((size_t)1024 * 1024 * 2);
    bf16* w1T = (bf16*)alloc((size_t)1024 * 2048 * 2);
    bf16* w2T = (bf16*)alloc((size_t)128 * 1024 * 2);
    bf16* featsA = (bf16*)alloc((size_t)3920 * 2048 * 2);
    char* regB = alloc(63176704);              // xg0; reused after recurrence
    float* xg0  = (float*)regB;
    bf16* qbf   = (bf16*)regB;                           // 3920*1024*2 = 8028160
    bf16* attnb = (bf16*)(regB + 8028160);               // 15488*512*2 = 15859712
    float* ctxf = (float*)(regB + 8028160 + 15859712);   // 3856*1024*4 = 15794176
    bf16* xbf   = (bf16*)(regB + 39682048);              // 3920*1024*2
    bf16* embb  = (bf16*)alloc((size_t)3920 * 1024 * 2);
    bf16* encb  = (bf16*)alloc((size_t)8192 * 1024 * 2);
    bf16* wih0b = (bf16*)alloc((size_t)4096 * 1024 * 2);
    bf16* whh0b = (bf16*)alloc((size_t)4096 * 1024 * 2);
    bf16* w1pk  = (bf16*)alloc((size_t)4096 * 2048 * 2);
    bf16* wkT = (bf16*)alloc((size_t)1024 * 1024 * 2);
    bf16* wvT = (bf16*)alloc((size_t)1024 * 1024 * 2);
    (void)ws_size; (void)in_sizes; (void)n_in;

    auto gemm = [&](const bf16* A, long sAb, long sAh, int lda,
                    const bf16* Bt, long sBb, long sBh, int ldb,
                    float* C, long sCb, long sCh, int ldc,
                    bf16* Cb, long sCbb, long sCbh, int ldcb,
                    const float* bc, const float* br,
                    int M, int N, int K, int nh, int act, int Z) {
        GemmArgs ga{A, sAb, sAh, lda, Bt, sBb, sBh, ldb, C, sCb, sCh, ldc,
                    Cb, sCbb, sCbh, ldcb, bc, br, M, N, K, nh, act};
        dim3 grid((N + 63) / 64, (M + 63) / 64, Z);
        gemm_bt<<<grid, 256, 0, stream>>>(ga);
    };

    // prep  (zero h0buf + A1buf + flags = (65536+131072+4096)/4 = 50176 words)
    zero_fill<<<64, 256, 0, stream>>>((unsigned*)h0buf, 50176);
    bias_sum<<<16, 256, 0, stream>>>(bih0, bhh0, bih1, bhh1, bias0, bias1f);
    seg_scan<<<1, 64, 0, stream>>>(targets, meta);
    embed_gather<<<2048, 256, 0, stream>>>(targets, embw, embb, (long)BT_ * 1024);
    f2bf<<<2048, 256, 0, stream>>>(enc, encb, (long)8192 * 1024);
    f2bf<<<2048, 256, 0, stream>>>(wih0, wih0b, (long)4096 * 1024);
    f2bf<<<2048, 256, 0, stream>>>(whh0, whh0b, (long)4096 * 1024);
    pack_w1<<<2048, 256, 0, stream>>>(wih1, whh1, w1pk);
    transpose_bf16<<<dim3(32, 32), 256, 0, stream>>>(wq, wqT, 1024, 1024, 1024);
    transpose_bf16<<<dim3(32, 32), 256, 0, stream>>>(wk, wkT, 1024, 1024, 1024);
    transpose_bf16<<<dim3(32, 32), 256, 0, stream>>>(wv, wvT, 1024, 1024, 1024);
    transpose_bf16<<<dim3(64, 32), 256, 0, stream>>>(w1, w1T, 2048, 1024, 1024);
    transpose_bf16<<<dim3(32, 4), 256, 0, stream>>>(w2, w2T, 1024, 100, 128);

    // k = enc*wk + bk   (8192x1024)
    gemm(encb, 0, 0, 1024, wkT, 0, 0, 1024, (float*)0, 0, 0, 0,
         kbf, 0, 0, 1024, bk, (const float*)0, 8192, 1024, 1024, 1, 0, 1);
    // vT[b][d][j] = (enc[b]*wv + bv)^T   (Z=16)
    gemm(wvT, 0, 0, 1024, encb, (long)512 * 1024, 0, 1024, (float*)0, 0, 0, 0,
         vT, (long)1024 * 512, 0, 512, (const float*)0, bv, 1024, 512, 1024, 1, 0, 16);
    // xg0 = emb*wih0^T + (bih0+bhh0)
    gemm(embb, 0, 0, 1024, wih0b, 0, 0, 1024, xg0, 0, 0, 4096,
         (bf16*)0, 0, 0, 0, bias0, (const float*)0, BT_, 4096, 1024, 1, 0, 1);

    // recurrence: one persistent kernel, flag-array sync
    lstm_persist<<<256, 256, 0, stream>>>(whh0b, w1pk, xg0, bias1f,
                                          h0buf, A1buf, featsA, flags);

    // q = h1*wq + bq
    gemm(featsA, 0, 0, 2048, wqT, 0, 0, 1024, (float*)0, 0, 0, 0,
         qbf, 0, 0, 1024, bq, (const float*)0, BT_, 1024, 1024, 1, 0, 1);
    // scores (raw) into d_out attn region, Z = 64 (b,h)
    float* attnOut = (float*)d_out + OUT0_;
    gemm(qbf, (long)241 * 1024, 256, 1024, kbf, (long)512 * 1024, 256, 1024,
         attnOut, (long)4 * 241 * 512, (long)241 * 512, 512,
         (bf16*)0, 0, 0, 0, (const float*)0, (const float*)0, 241, 512, 256, 4, 0, 64);
    attn_softmax<<<3856, 256, 0, stream>>>(attnOut, attnb, 15424);
    // ctx = attn*v -> ctx_f32 and featsA[:,1024:]
    gemm(attnb, (long)4 * 241 * 512, (long)241 * 512, 512,
         vT, (long)1024 * 512, (long)256 * 512, 512,
         ctxf, (long)241 * 1024, 256, 1024,
         featsA + 1024, (long)241 * 2048, 256, 2048,
         (const float*)0, (const float*)0, 241, 256, 512, 4, 0, 64);
    // x = tanh(feats*w1 + b1)
    gemm(featsA, 0, 0, 2048, w1T, 0, 0, 2048, (float*)0, 0, 0, 0,
         xbf, 0, 0, 1024, b1, (const float*)0, BT_, 1024, 2048, 1, 1, 1);
    // logits -> d_out[0:385600]
    gemm(xbf, 0, 0, 1024, w2T, 0, 0, 1024, (float*)d_out, 0, 0, 100,
         (bf16*)0, 0, 0, 0, b2, (const float*)0, BT_, 100, 1024, 1, 0, 1);
    logsoftmax_k<<<964, 256, 0, stream>>>((float*)d_out, BT_);

    long wn = (long)out_size - OUT0_ - OUT1_;
    if (wn > 0)
        words_fill<<<2048, 256, 0, stream>>>(meta, targets, embw, ctxf,
                                             (float*)d_out + OUT0_ + OUT1_, wn);
}